// Round 8
// baseline (671.715 us; speedup 1.0000x reference)
//
#include <hip/hip_runtime.h>
#include <math.h>

// Problem constants (B=16, N=2048, C=512)
#define BB 16
#define NN 2048
#define CC 512
#define MM (BB * NN)   // 32768 flattened rows
#define NSPLIT 4       // range-split factor for attention passes

typedef _Float16 half8 __attribute__((ext_vector_type(8)));
typedef _Float16 half4 __attribute__((ext_vector_type(4)));
typedef float floatx4 __attribute__((ext_vector_type(4)));

// async global->LDS, 16B/lane; LDS dest = wave-uniform base + lane*16
#define GLD16(gp, lp) __builtin_amdgcn_global_load_lds( \
    (const __attribute__((address_space(1))) void*)(gp), \
    (__attribute__((address_space(3))) void*)(lp), 16, 0, 0)

// LDS tile layout: 16-row groups, 32 halves (64B) per row, quad(16B)-XOR-swizzled:
// slot quad q' holds global quad q' ^ ((row>>1)&3)  -> b128 frag reads are 2-way
// conflict (free) instead of 8-way. Same XOR on stage & read (self-inverse).
__device__ __forceinline__ int foff(int row16base, int fr, int g4) {
    return (row16base + fr) * 32 + ((g4 ^ ((fr >> 1) & 3)) << 3);
}

// ---------------------------------------------------------------------------
// split x (fp32) -> xh + xl (f16 hi/lo), elementwise, float4-vectorized
// ---------------------------------------------------------------------------
__global__ __launch_bounds__(256)
void split_x(const float* __restrict__ x, _Float16* __restrict__ xh,
             _Float16* __restrict__ xl)
{
    const size_t i = ((size_t)blockIdx.x * 256 + threadIdx.x) * 4;
    const float4 v = *(const float4*)(x + i);
    half4 h, l;
    h[0] = (_Float16)v.x; l[0] = (_Float16)(v.x - (float)h[0]);
    h[1] = (_Float16)v.y; l[1] = (_Float16)(v.y - (float)h[1]);
    h[2] = (_Float16)v.z; l[2] = (_Float16)(v.z - (float)h[2]);
    h[3] = (_Float16)v.w; l[3] = (_Float16)(v.w - (float)h[3]);
    *(half4*)(xh + i) = h;
    *(half4*)(xl + i) = l;
}

// ---------------------------------------------------------------------------
// Wt[n*512+k] = f16(W[k*512+n])  (512x512 transpose+convert, tiny)
// ---------------------------------------------------------------------------
__global__ __launch_bounds__(256)
void conv_wT(const float* __restrict__ W, _Float16* __restrict__ Wt)
{
    const int o = blockIdx.x * 256 + threadIdx.x;   // o = n*512 + k
    const int n = o >> 9, k = o & 511;
    Wt[o] = (_Float16)W[k * 512 + n];
}

// ---------------------------------------------------------------------------
// w2[c] = sum_j Wk[c][j] * bq[j]   (beta helper; bq==0 at runtime)
// ---------------------------------------------------------------------------
__global__ __launch_bounds__(256)
void calc_w2(const float* __restrict__ Wk, const float* __restrict__ bq,
             float* __restrict__ w2)
{
    const int i = blockIdx.x * 256 + threadIdx.x;
    if (i < 512) {
        float s = 0.0f;
        for (int j = 0; j < 512; ++j) s += Wk[i * 512 + j] * bq[j];
        w2[i] = s;
    }
}

// ---------------------------------------------------------------------------
// bet[m] = x_m . w2   (one wave per row)
// ---------------------------------------------------------------------------
__global__ __launch_bounds__(256)
void calc_beta(const float* __restrict__ x, const float* __restrict__ w2,
               float* __restrict__ bet)
{
    const int w = threadIdx.x >> 6, lane = threadIdx.x & 63;
    const int m = blockIdx.x * 4 + w;
    const float* xr = x + (size_t)m * CC;
    float s = 0.0f;
    for (int c = lane; c < CC; c += 64) s += xr[c] * w2[c];
    for (int off = 1; off < 64; off <<= 1) s += __shfl_xor(s, off);
    if (lane == 0) bet[m] = s;
}

// ---------------------------------------------------------------------------
// Pt[j][i] = sum_c Wk[j][c]*Wq[i][c]  (= P^T, P = Wq Wk^T), fp32, split-store.
// ---------------------------------------------------------------------------
__global__ __launch_bounds__(256)
void gemm_nt_split(const float* __restrict__ A, const float* __restrict__ Bm,
                   _Float16* __restrict__ outh, _Float16* __restrict__ outl)
{
    __shared__ float As[16][64];
    __shared__ float Bs[16][64];
    const int t = threadIdx.x, tc = t & 15, tr = t >> 4;
    const int j0 = blockIdx.x * 64, i0 = blockIdx.y * 64;
    const int lm = t >> 2, lk4 = (t & 3) << 2;
    float acc[4][4] = {};
    for (int kt = 0; kt < 512; kt += 16) {
        const float4 xa = *(const float4*)(A + (size_t)(j0 + lm) * 512 + kt + lk4);
        As[lk4 + 0][lm] = xa.x; As[lk4 + 1][lm] = xa.y;
        As[lk4 + 2][lm] = xa.z; As[lk4 + 3][lm] = xa.w;
        const float4 xb = *(const float4*)(Bm + (size_t)(i0 + lm) * 512 + kt + lk4);
        Bs[lk4 + 0][lm] = xb.x; Bs[lk4 + 1][lm] = xb.y;
        Bs[lk4 + 2][lm] = xb.z; Bs[lk4 + 3][lm] = xb.w;
        __syncthreads();
#pragma unroll
        for (int k = 0; k < 16; ++k) {
            float av[4], bv[4];
            *(float4*)av = *(const float4*)&As[k][tr * 4];
            *(float4*)bv = *(const float4*)&Bs[k][tc * 4];
#pragma unroll
            for (int i = 0; i < 4; ++i)
#pragma unroll
                for (int j = 0; j < 4; ++j)
                    acc[i][j] = fmaf(av[i], bv[j], acc[i][j]);
        }
        __syncthreads();
    }
#pragma unroll
    for (int i = 0; i < 4; ++i) {
        const int row = j0 + tr * 4 + i;
#pragma unroll
        for (int j = 0; j < 4; ++j) {
            const int col = i0 + tc * 4 + j;
            const float y = acc[i][j];
            const _Float16 h = (_Float16)y;
            outh[row * 512 + col] = h;
            outl[row * 512 + col] = (_Float16)(y - (float)h);
        }
    }
}

// ---------------------------------------------------------------------------
// f16 MFMA GEMM: Y[M x 512] = A[M x 512] @ Bt^T. 128x256 tile, 4 waves,
// acc 4x8. 3-buffer depth-2 counted-vmcnt pipeline (proven in attn passes):
// stage = 6 GLD16 (A:2, B:4); at tile t issue loads for t+2, compute t,
// s_waitcnt vmcnt(6). SPLIT: Al/Bl operands are wave-private -> straight
// global->register loads, issued FIRST so the compiler's auto-wait before
// their MFMA use is vmcnt(6) (keeps the t+2 stage in flight).
// MODE 0 (SPLIT): split-store oh/ol (a-GEMM, 3-term hi/lo)
// MODE 1: oh = f16((acc + bias[col]) * colsc[row])            (v-GEMM)
// MODE 2: outf = relu(BN(acc + bias)) + xres                  (out-GEMM)
// ---------------------------------------------------------------------------
template<bool SPLIT, int MODE>
__global__ __launch_bounds__(256, 2)
void gemm16(const _Float16* __restrict__ Ah, const _Float16* __restrict__ Al,
            const _Float16* __restrict__ Bh, const _Float16* __restrict__ Bl,
            const float* __restrict__ bias, const float* __restrict__ colsc,
            const float* __restrict__ bn_scale, const float* __restrict__ bn_bias,
            const float* __restrict__ bn_mean, const float* __restrict__ bn_var,
            const float* __restrict__ xres,
            _Float16* __restrict__ oh, _Float16* __restrict__ ol,
            float* __restrict__ outf)
{
    __shared__ __align__(16) _Float16 sA0[128 * 32], sA1[128 * 32], sA2[128 * 32];
    __shared__ __align__(16) _Float16 sB0[256 * 32], sB1[256 * 32], sB2[256 * 32];

    const int t = threadIdx.x, lane = t & 63, w = t >> 6;
    const int m0 = blockIdx.x * 128, n0 = blockIdx.y * 256;
    const int lr4 = lane >> 2;
    const int sw8 = (((lane & 3) ^ ((lr4 >> 1) & 3)) << 3);
    const int fr = lane & 15, g4 = lane >> 4;
    const int wr = (w >> 1) * 64, wc = (w & 1) * 128;

    floatx4 acc[4][8];
#pragma unroll
    for (int i = 0; i < 4; ++i)
#pragma unroll
        for (int j = 0; j < 8; ++j) acc[i][j] = (floatx4){0.f, 0.f, 0.f, 0.f};

    auto stage = [&](_Float16* Sa, _Float16* Sb, int gt) {
        const int kt = gt * 32;
#pragma unroll
        for (int c = 0; c < 2; ++c) {          // A: 128 rows
            const int r = w * 32 + c * 16;
            GLD16(Ah + (size_t)(m0 + r + lr4) * CC + kt + sw8, Sa + r * 32);
        }
#pragma unroll
        for (int c = 0; c < 4; ++c) {          // B: 256 rows
            const int r = w * 64 + c * 16;
            GLD16(Bh + (size_t)(n0 + r + lr4) * CC + kt + sw8, Sb + r * 32);
        }
    };

    // mode: 0 = stage(t+2)+vmcnt(6), 1 = no stage+vmcnt(0), 2 = tail
    auto tile = [&](const _Float16* Ra, const _Float16* Rb,
                    _Float16* Sa, _Float16* Sb, int gt, int mode) {
        const int kt = gt * 32;
        half8 fal[4], fbl[8];                   // SPLIT lo-operands to regs FIRST
        if constexpr (SPLIT) {
#pragma unroll
            for (int rt = 0; rt < 4; ++rt)
                fal[rt] = *(const half8*)(Al + (size_t)(m0 + wr + rt * 16 + fr) * CC
                                          + kt + g4 * 8);
#pragma unroll
            for (int ct = 0; ct < 8; ++ct)
                fbl[ct] = *(const half8*)(Bl + (size_t)(n0 + wc + ct * 16 + fr) * CC
                                          + kt + g4 * 8);
        }
        if (mode == 0) stage(Sa, Sb, gt + 2);
        half8 fa[4];
#pragma unroll
        for (int rt = 0; rt < 4; ++rt)
            fa[rt] = *(const half8*)&Ra[foff(wr + rt * 16, fr, g4)];
#pragma unroll
        for (int hh = 0; hh < 2; ++hh) {        // two ct-halves bound VGPRs
            half8 fb[4];
#pragma unroll
            for (int c4 = 0; c4 < 4; ++c4)
                fb[c4] = *(const half8*)&Rb[foff(wc + (hh * 4 + c4) * 16, fr, g4)];
            __builtin_amdgcn_s_setprio(1);
#pragma unroll
            for (int rt = 0; rt < 4; ++rt)
#pragma unroll
                for (int c4 = 0; c4 < 4; ++c4) {
                    const int ct = hh * 4 + c4;
                    acc[rt][ct] = __builtin_amdgcn_mfma_f32_16x16x32_f16(
                        fa[rt], fb[c4], acc[rt][ct], 0, 0, 0);
                    if constexpr (SPLIT) {
                        acc[rt][ct] = __builtin_amdgcn_mfma_f32_16x16x32_f16(
                            fa[rt], fbl[ct], acc[rt][ct], 0, 0, 0);
                        acc[rt][ct] = __builtin_amdgcn_mfma_f32_16x16x32_f16(
                            fal[rt], fb[c4], acc[rt][ct], 0, 0, 0);
                    }
                }
            __builtin_amdgcn_s_setprio(0);
        }
        if (mode == 0)      asm volatile("s_waitcnt vmcnt(6)" ::: "memory");
        else if (mode == 1) asm volatile("s_waitcnt vmcnt(0)" ::: "memory");
        __builtin_amdgcn_s_barrier();
        asm volatile("" ::: "memory");
    };

    stage(sA0, sB0, 0);
    stage(sA1, sB1, 1);
    asm volatile("s_waitcnt vmcnt(6)" ::: "memory");
    __builtin_amdgcn_s_barrier();
    asm volatile("" ::: "memory");

#pragma unroll 1
    for (int u = 0; u < 4; ++u) {              // tiles 0..11
        const int gt = u * 3;
        tile(sA0, sB0, sA2, sB2, gt,     0);
        tile(sA1, sB1, sA0, sB0, gt + 1, 0);
        tile(sA2, sB2, sA1, sB1, gt + 2, 0);
    }
    tile(sA0, sB0, sA2, sB2, 12, 0);
    tile(sA1, sB1, sA0, sB0, 13, 0);
    tile(sA2, sB2, nullptr, nullptr, 14, 1);
    tile(sA0, sB0, nullptr, nullptr, 15, 2);

#pragma unroll
    for (int rt = 0; rt < 4; ++rt)
#pragma unroll
        for (int ct = 0; ct < 8; ++ct) {
            const int col = n0 + wc + ct * 16 + fr;
#pragma unroll
            for (int reg = 0; reg < 4; ++reg) {
                const int row = m0 + wr + rt * 16 + g4 * 4 + reg;
                float y = acc[rt][ct][reg];
                if constexpr (MODE == 0) {
                    const _Float16 h = (_Float16)y;
                    oh[(size_t)row * CC + col] = h;
                    ol[(size_t)row * CC + col] = (_Float16)(y - (float)h);
                } else if constexpr (MODE == 1) {
                    y = (y + bias[col]) * colsc[row];
                    oh[(size_t)row * CC + col] = (_Float16)y;
                } else {
                    y += bias[col];
                    y = (y - bn_mean[col]) * rsqrtf(bn_var[col] + 1e-5f)
                            * bn_scale[col] + bn_bias[col];
                    y = fmaxf(y, 0.0f) + xres[(size_t)row * CC + col];
                    outf[(size_t)row * CC + col] = y;
                }
            }
        }
}

// ---------------------------------------------------------------------------
// XCD-grouping remaps (proven: FETCH 656 -> 541 MB). Rowstats grid (16,16,4):
// h = bx + 16by + 256bz; xt=(h>>3)&15; g=((h>>7)<<3)|(h&7); b=g&15; sp=g>>4.
// Colsum grid (8,16,4):  h = bx +  8by + 128bz; xt=(h>>3)&7;
//                        g=((h>>6)<<3)|(h&7); b=g&15; sp=g>>4.
// All xt-siblings of a (b,sp) group sit at h == g (mod 8) -> same XCD L2.
// ---------------------------------------------------------------------------
__device__ __forceinline__ void attn_decode3(int& xt, int& b, int& sp) {
    const int h = blockIdx.x + (blockIdx.y << 4) + (blockIdx.z << 8);
    xt = (h >> 3) & 15;
    const int g = ((h >> 7) << 3) | (h & 7);
    b = g & 15;
    sp = g >> 4;
}
__device__ __forceinline__ void attn_decode_col(int& xt, int& b, int& sp) {
    const int h = blockIdx.x + (blockIdx.y << 3) + (blockIdx.z << 7);
    xt = (h >> 3) & 7;
    const int g = ((h >> 6) << 3) | (h & 7);
    b = g & 15;
    sp = g >> 4;
}

// ---------------------------------------------------------------------------
// Pass A: partial online-softmax stats over an n-range of 512.
// Grid (16,16,4), XCD-remapped. Block: 128 m-rows x 2 n-chunks of 256.
// 32 k-tiles total (2 chunks x 16), 3-buffer depth-2 counted-vmcnt pipeline.
// LDS: Ah (hi A) + X per buffer (24 KB x3); al (lo A) goes global->register
// per wave (rows are wave-private), issued FIRST in each body so the
// compiler's auto-wait before its MFMA use is vmcnt(6) -> keeps the t+2
// stage in flight. acc 4x8 (64 MFMA/tile/wave = 2x duty per barrier).
// ---------------------------------------------------------------------------
__global__ __launch_bounds__(256, 2)
void attn_rowstats(const _Float16* __restrict__ ah_, const _Float16* __restrict__ al_,
                   const _Float16* __restrict__ xh_,
                   const float* __restrict__ bet,
                   float* __restrict__ pm, float* __restrict__ pl)
{
    __shared__ __align__(16) _Float16 A0[128 * 32], A1[128 * 32], A2[128 * 32];
    __shared__ __align__(16) _Float16 X0[256 * 32], X1[256 * 32], X2[256 * 32];
    __shared__ float wm[4][64], wl[4][64];

    int xt, b, sp;
    attn_decode3(xt, b, sp);
    const int m0 = xt * 128;
    const int t = threadIdx.x, lane = t & 63, w = t >> 6;
    const int lr4 = lane >> 2;
    const int sw8 = (((lane & 3) ^ ((lr4 >> 1) & 3)) << 3);
    const int fr = lane & 15, g4 = lane >> 4;
    const int wr = (w >> 1) * 64, wc = (w & 1) * 128;
    const size_t bbase = (size_t)b * NN;

    // bet for both 256-wide chunks, preloaded (no mid-loop VMEM)
    float betA[8], betB[8];
#pragma unroll
    for (int ct = 0; ct < 8; ++ct) {
        betA[ct] = bet[bbase + sp * 512 +   0 + wc + ct * 16 + fr];
        betB[ct] = bet[bbase + sp * 512 + 256 + wc + ct * 16 + fr];
    }

    float m_st[4][4], l_st[4][4];
#pragma unroll
    for (int i = 0; i < 4; ++i)
#pragma unroll
        for (int j = 0; j < 4; ++j) { m_st[i][j] = -3.0e38f; l_st[i][j] = 0.0f; }

    floatx4 acc[4][8];
#pragma unroll
    for (int i = 0; i < 4; ++i)
#pragma unroll
        for (int j = 0; j < 8; ++j) acc[i][j] = (floatx4){0.f, 0.f, 0.f, 0.f};

    auto stage = [&](_Float16* Sa, _Float16* Sx, int gt) {
        const int nn0 = sp * 512 + (gt >> 4) * 256;
        const int nkt = (gt & 15) * 32;
#pragma unroll
        for (int c = 0; c < 2; ++c) {          // A-hi: 128 rows
            const int r = w * 32 + c * 16;
            GLD16(ah_ + (bbase + m0 + r + lr4) * CC + nkt + sw8, Sa + r * 32);
        }
#pragma unroll
        for (int c = 0; c < 4; ++c) {          // X: 256 rows
            const int r = w * 64 + c * 16;
            GLD16(xh_ + (bbase + nn0 + r + lr4) * CC + nkt + sw8, Sx + r * 32);
        }
    };

    // mode: 0 = stage(t+2)+vmcnt(6), 1 = no stage+vmcnt(0), 2 = tail
    auto tile = [&](const _Float16* Ra, const _Float16* Rx,
                    _Float16* Sa, _Float16* Sx, int gt, int mode) {
        const int kt = (gt & 15) * 32;
        half8 fal[4];                           // A-lo straight to regs (FIRST)
#pragma unroll
        for (int rt = 0; rt < 4; ++rt)
            fal[rt] = *(const half8*)(al_ + (bbase + m0 + wr + rt * 16 + fr) * CC
                                      + kt + g4 * 8);
        if (mode == 0) stage(Sa, Sx, gt + 2);
        half8 fa[4];
#pragma unroll
        for (int rt = 0; rt < 4; ++rt)
            fa[rt] = *(const half8*)&Ra[foff(wr + rt * 16, fr, g4)];
#pragma unroll
        for (int hh = 0; hh < 2; ++hh) {        // two ct-halves bound VGPRs
            half8 fb[4];
#pragma unroll
            for (int c4 = 0; c4 < 4; ++c4)
                fb[c4] = *(const half8*)&Rx[foff(wc + (hh * 4 + c4) * 16, fr, g4)];
            __builtin_amdgcn_s_setprio(1);
#pragma unroll
            for (int rt = 0; rt < 4; ++rt)
#pragma unroll
                for (int c4 = 0; c4 < 4; ++c4) {
                    acc[rt][hh * 4 + c4] = __builtin_amdgcn_mfma_f32_16x16x32_f16(
                        fa[rt], fb[c4], acc[rt][hh * 4 + c4], 0, 0, 0);
                    acc[rt][hh * 4 + c4] = __builtin_amdgcn_mfma_f32_16x16x32_f16(
                        fal[rt], fb[c4], acc[rt][hh * 4 + c4], 0, 0, 0);
                }
            __builtin_amdgcn_s_setprio(0);
        }
        if ((gt & 15) == 15) {                  // chunk end: softmax update
            const bool c1 = (gt >> 4) != 0;
#pragma unroll
            for (int rt = 0; rt < 4; ++rt)
#pragma unroll
                for (int reg = 0; reg < 4; ++reg) {
                    float v[8];
#pragma unroll
                    for (int ct = 0; ct < 8; ++ct)
                        v[ct] = acc[rt][ct][reg] + (c1 ? betB[ct] : betA[ct]);
                    float mx = v[0];
#pragma unroll
                    for (int ct = 1; ct < 8; ++ct) mx = fmaxf(mx, v[ct]);
                    const float mo = m_st[rt][reg];
                    const float mn = fmaxf(mo, mx);
                    float s = 0.0f;
#pragma unroll
                    for (int ct = 0; ct < 8; ++ct) s += __expf(v[ct] - mn);
                    l_st[rt][reg] = l_st[rt][reg] * __expf(mo - mn) + s;
                    m_st[rt][reg] = mn;
                }
#pragma unroll
            for (int i = 0; i < 4; ++i)
#pragma unroll
                for (int j = 0; j < 8; ++j) acc[i][j] = (floatx4){0.f, 0.f, 0.f, 0.f};
        }
        if (mode == 0)      asm volatile("s_waitcnt vmcnt(6)" ::: "memory");
        else if (mode == 1) asm volatile("s_waitcnt vmcnt(0)" ::: "memory");
        __builtin_amdgcn_s_barrier();
        asm volatile("" ::: "memory");
    };

    stage(A0, X0, 0);
    stage(A1, X1, 1);
    asm volatile("s_waitcnt vmcnt(6)" ::: "memory");
    __builtin_amdgcn_s_barrier();
    asm volatile("" ::: "memory");

#pragma unroll 1
    for (int u = 0; u < 10; ++u) {
        const int gt = u * 3;
        tile(A0, X0, A2, X2, gt,     0);
        tile(A1, X1, A0, X0, gt + 1, 0);
        tile(A2, X2, A1, X1, gt + 2, 0);
    }
    tile(A0, X0, nullptr, nullptr, 30, 1);
    tile(A1, X1, nullptr, nullptr, 31, 2);

    // merge across 16 col-lanes, then across the col-wave pair via LDS
#pragma unroll
    for (int rt = 0; rt < 4; ++rt)
#pragma unroll
        for (int reg = 0; reg < 4; ++reg) {
            float m = m_st[rt][reg], l = l_st[rt][reg];
#pragma unroll
            for (int off = 1; off < 16; off <<= 1) {
                const float mo = __shfl_xor(m, off);
                const float lo = __shfl_xor(l, off);
                const float mn = fmaxf(m, mo);
                l = l * __expf(m - mn) + lo * __expf(mo - mn);
                m = mn;
            }
            if (fr == 0) {
                wm[w][rt * 16 + g4 * 4 + reg] = m;
                wl[w][rt * 16 + g4 * 4 + reg] = l;
            }
        }
    __syncthreads();
    if (t < 128) {
        const int r = t & 63;
        const int wa = (t < 64) ? 0 : 2, wb = wa + 1;
        const float ma = wm[wa][r], mb = wm[wb][r];
        const float M = fmaxf(ma, mb);
        const float L = wl[wa][r] * __expf(ma - M) + wl[wb][r] * __expf(mb - M);
        pm[(size_t)sp * MM + bbase + m0 + t] = M;
        pl[(size_t)sp * MM + bbase + m0 + t] = L;
    }
}

// ---------------------------------------------------------------------------
// rho[m] = M + log(sum_s pl[s]*exp(pm[s]-M)),  M = max_s pm[s]
// ---------------------------------------------------------------------------
__global__ __launch_bounds__(256)
void rho_merge(const float* __restrict__ pm, const float* __restrict__ pl,
               float* __restrict__ rho)
{
    const size_t i = (size_t)blockIdx.x * 256 + threadIdx.x;
    float M = pm[i];
#pragma unroll
    for (int s = 1; s < NSPLIT; ++s) M = fmaxf(M, pm[s * (size_t)MM + i]);
    float L = 0.0f;
#pragma unroll
    for (int s = 0; s < NSPLIT; ++s)
        L += pl[s * (size_t)MM + i] * __expf(pm[s * (size_t)MM + i] - M);
    rho[i] = M + __logf(L);
}

// ---------------------------------------------------------------------------
// Pass B: partial column sums over an m-range of 512.
// Grid (8,16,4), XCD-remapped. Block: 256 n-cols x 4 m-chunks of 128.
// 64 k-tiles, same 3-buffer depth-2 pipeline, al->regs, acc 4x8.
// pc[split][b*NN+n] = sum_{m in range} exp(s + bet[n] - rho[m]).
// ---------------------------------------------------------------------------
__global__ __launch_bounds__(256, 2)
void attn_colsum(const _Float16* __restrict__ ah_, const _Float16* __restrict__ al_,
                 const _Float16* __restrict__ xh_,
                 const float* __restrict__ bet, const float* __restrict__ rho,
                 float* __restrict__ pc)
{
    __shared__ __align__(16) _Float16 A0[128 * 32], A1[128 * 32], A2[128 * 32];
    __shared__ __align__(16) _Float16 X0[256 * 32], X1[256 * 32], X2[256 * 32];
    __shared__ float cred[4][128];

    int xt, b, sp;
    attn_decode_col(xt, b, sp);
    const int n0 = xt * 256;
    const int t = threadIdx.x, lane = t & 63, w = t >> 6;
    const int lr4 = lane >> 2;
    const int sw8 = (((lane & 3) ^ ((lr4 >> 1) & 3)) << 3);
    const int fr = lane & 15, g4 = lane >> 4;
    const int wr = (w >> 1) * 64, wc = (w & 1) * 128;
    const size_t bbase = (size_t)b * NN;

    float bet_r[8];
#pragma unroll
    for (int ct = 0; ct < 8; ++ct)
        bet_r[ct] = bet[bbase + n0 + wc + ct * 16 + fr];

    float csum[8] = {0.f, 0.f, 0.f, 0.f, 0.f, 0.f, 0.f, 0.f};
    floatx4 rr[4];
    floatx4 acc[4][8];
#pragma unroll
    for (int i = 0; i < 4; ++i)
#pragma unroll
        for (int j = 0; j < 8; ++j) acc[i][j] = (floatx4){0.f, 0.f, 0.f, 0.f};

    auto stage = [&](_Float16* Sa, _Float16* Sx, int gt) {
        const int nm0 = sp * 512 + (gt >> 4) * 128;
        const int nkt = (gt & 15) * 32;
#pragma unroll
        for (int c = 0; c < 2; ++c) {          // A-hi: 128 m-rows (chunk)
            const int r = w * 32 + c * 16;
            GLD16(ah_ + (bbase + nm0 + r + lr4) * CC + nkt + sw8, Sa + r * 32);
        }
#pragma unroll
        for (int c = 0; c < 4; ++c) {          // X: 256 n-rows (fixed panel)
            const int r = w * 64 + c * 16;
            GLD16(xh_ + (bbase + n0 + r + lr4) * CC + nkt + sw8, Sx + r * 32);
        }
    };

    auto tile = [&](const _Float16* Ra, const _Float16* Rx,
                    _Float16* Sa, _Float16* Sx, int gt, int mode) {
        const int kt = (gt & 15) * 32;
        const int m0c = sp * 512 + (gt >> 4) * 128;
        if ((gt & 15) == 0) {                   // chunk start: rho -> regs
#pragma unroll
            for (int rt = 0; rt < 4; ++rt)
                rr[rt] = *(const floatx4*)&rho[bbase + m0c + wr + rt * 16 + g4 * 4];
        }
        half8 fal[4];                           // A-lo to regs (FIRST)
#pragma unroll
        for (int rt = 0; rt < 4; ++rt)
            fal[rt] = *(const half8*)(al_ + (bbase + m0c + wr + rt * 16 + fr) * CC
                                      + kt + g4 * 8);
        if (mode == 0) stage(Sa, Sx, gt + 2);
        half8 fa[4];
#pragma unroll
        for (int rt = 0; rt < 4; ++rt)
            fa[rt] = *(const half8*)&Ra[foff(wr + rt * 16, fr, g4)];
#pragma unroll
        for (int hh = 0; hh < 2; ++hh) {
            half8 fb[4];
#pragma unroll
            for (int c4 = 0; c4 < 4; ++c4)
                fb[c4] = *(const half8*)&Rx[foff(wc + (hh * 4 + c4) * 16, fr, g4)];
            __builtin_amdgcn_s_setprio(1);
#pragma unroll
            for (int rt = 0; rt < 4; ++rt)
#pragma unroll
                for (int c4 = 0; c4 < 4; ++c4) {
                    acc[rt][hh * 4 + c4] = __builtin_amdgcn_mfma_f32_16x16x32_f16(
                        fa[rt], fb[c4], acc[rt][hh * 4 + c4], 0, 0, 0);
                    acc[rt][hh * 4 + c4] = __builtin_amdgcn_mfma_f32_16x16x32_f16(
                        fal[rt], fb[c4], acc[rt][hh * 4 + c4], 0, 0, 0);
                }
            __builtin_amdgcn_s_setprio(0);
        }
        if ((gt & 15) == 15) {                  // chunk end: colsum accumulate
#pragma unroll
            for (int rt = 0; rt < 4; ++rt)
#pragma unroll
                for (int reg = 0; reg < 4; ++reg) {
                    const float r = rr[rt][reg];
#pragma unroll
                    for (int ct = 0; ct < 8; ++ct)
                        csum[ct] += __expf(acc[rt][ct][reg] + bet_r[ct] - r);
                }
#pragma unroll
            for (int i = 0; i < 4; ++i)
#pragma unroll
                for (int j = 0; j < 8; ++j) acc[i][j] = (floatx4){0.f, 0.f, 0.f, 0.f};
        }
        if (mode == 0)      asm volatile("s_waitcnt vmcnt(6)" ::: "memory");
        else if (mode == 1) asm volatile("s_waitcnt vmcnt(0)" ::: "memory");
        __builtin_amdgcn_s_barrier();
        asm volatile("" ::: "memory");
    };

    stage(A0, X0, 0);
    stage(A1, X1, 1);
    asm volatile("s_waitcnt vmcnt(6)" ::: "memory");
    __builtin_amdgcn_s_barrier();
    asm volatile("" ::: "memory");

#pragma unroll 1
    for (int u = 0; u < 20; ++u) {
        const int gt = u * 3;
        tile(A0, X0, A2, X2, gt,     0);
        tile(A1, X1, A0, X0, gt + 1, 0);
        tile(A2, X2, A1, X1, gt + 2, 0);
    }
    tile(A0, X0, A2, X2, 60, 0);
    tile(A1, X1, A0, X0, 61, 0);
    tile(A2, X2, nullptr, nullptr, 62, 1);
    tile(A0, X0, nullptr, nullptr, 63, 2);

    // reduce over the 4 row-lane groups, then across the row-wave pair
#pragma unroll
    for (int ct = 0; ct < 8; ++ct) {
        csum[ct] += __shfl_xor(csum[ct], 16);
        csum[ct] += __shfl_xor(csum[ct], 32);
    }
    if (lane < 16)
#pragma unroll
        for (int ct = 0; ct < 8; ++ct) cred[w][ct * 16 + lane] = csum[ct];
    __syncthreads();
    if (t < 256) {
        const int c = t & 127;
        const float s = (t < 128) ? (cred[0][c] + cred[2][c])
                                  : (cred[1][c] + cred[3][c]);
        pc[(size_t)sp * MM + bbase + n0 + t] = s;
    }
}

// ---------------------------------------------------------------------------
// colsc[n] = c/(eps+c), c = sum over splits of pc
// ---------------------------------------------------------------------------
__global__ __launch_bounds__(256)
void colsc_merge(const float* __restrict__ pc, float* __restrict__ colsc)
{
    const size_t i = (size_t)blockIdx.x * 256 + threadIdx.x;
    float c = 0.0f;
#pragma unroll
    for (int s = 0; s < NSPLIT; ++s) c += pc[s * (size_t)MM + i];
    colsc[i] = c / (1e-9f + c);
}

// ---------------------------------------------------------------------------
// Workspace (128 MiB): xh|xl|ah|al (4 x M*C f16). th aliases al; Wvt/Wot
// go into ah (dead after passB). Small scratch in d_out (dead before the
// final out-GEMM writes it).
// ---------------------------------------------------------------------------
extern "C" void kernel_launch(void* const* d_in, const int* in_sizes, int n_in,
                              void* d_out, int out_size, void* d_ws, size_t ws_size,
                              hipStream_t stream)
{
    const float* x        = (const float*)d_in[0];
    const float* Wq       = (const float*)d_in[1];
    const float* bq       = (const float*)d_in[2];
    const float* Wk       = (const float*)d_in[3];
    const float* bk       = (const float*)d_in[4];   (void)bk;  // softmax-invariant
    const float* Wv       = (const float*)d_in[5];
    const float* bv       = (const float*)d_in[6];
    const float* Wo       = (const float*)d_in[7];
    const float* bo       = (const float*)d_in[8];
    const float* bn_scale = (const float*)d_in[9];
    const float* bn_bias  = (const float*)d_in[10];
    const float* bn_mean  = (const float*)d_in[11];
    const float* bn_var   = (const float*)d_in[12];
    float* out = (float*)d_out;

    const size_t MMC = (size_t)MM * CC;   // 16,777,216
    _Float16* xh = (_Float16*)d_ws;
    _Float16* xl = xh + MMC;
    _Float16* ah = xl + MMC;
    _Float16* al = ah + MMC;
    _Float16* th  = al;                    // v-GEMM output aliases al
    _Float16* Wvt = ah;                    // converted after passB (ah dead)
    _Float16* Wot = ah + 512 * 512;

    // small scratch in d_out (all consumed before the final GEMM writes out)
    char* ob = (char*)d_out;
    _Float16* Pth = (_Float16*)(ob);                        //  512 KiB
    _Float16* Ptl = (_Float16*)(ob + (1u << 19));           //  512 KiB
    float* w2     = (float*)(ob + (2u << 19));              //    2 KiB
    float* bet    = (float*)(ob + (2u << 19) + 8192);       //  128 KiB
    float* rho    = (float*)(ob + 1318912);                 //  128 KiB
    float* colsc  = (float*)(ob + 1449984);                 //  128 KiB
    float* pm     = (float*)(ob + 1581056);                 //  512 KiB
    float* pl     = (float*)(ob + 2105344);                 //  512 KiB
    float* pc     = (float*)(ob + 2629632);                 //  512 KiB

    const dim3 blk(256);
    const dim3 g16(MM / 128, CC / 256);        // 256 x 2 (128x256 tile)
    const dim3 grow(NN / 128, BB, NSPLIT);     // 16 x 16 x 4 (XCD-remapped)
    const dim3 gcol(NN / 256, BB, NSPLIT);     //  8 x 16 x 4 (XCD-remapped)

    split_x<<<MMC / (256 * 4), blk, 0, stream>>>(x, xh, xl);
    gemm_nt_split<<<dim3(8, 8), blk, 0, stream>>>(Wk, Wq, Pth, Ptl);
    calc_w2<<<2, blk, 0, stream>>>(Wk, bq, w2);
    calc_beta<<<MM / 4, blk, 0, stream>>>(x, w2, bet);

    // a = x @ (Wq Wk^T), split-stored (3-term)
    gemm16<true, 0><<<g16, blk, 0, stream>>>(xh, xl, Pth, Ptl,
        nullptr, nullptr, nullptr, nullptr, nullptr, nullptr, nullptr,
        ah, al, nullptr);

    attn_rowstats<<<grow, blk, 0, stream>>>(ah, al, xh, bet, pm, pl);
    rho_merge<<<MM / 256, blk, 0, stream>>>(pm, pl, rho);
    attn_colsum<<<gcol, blk, 0, stream>>>(ah, al, xh, bet, rho, pc);
    colsc_merge<<<MM / 256, blk, 0, stream>>>(pc, colsc);

    // th = f16(colsc[row] * (x @ Wv + bv))
    conv_wT<<<1024, blk, 0, stream>>>(Wv, Wvt);
    gemm16<false, 1><<<g16, blk, 0, stream>>>(xh, nullptr, Wvt, nullptr,
        bv, colsc, nullptr, nullptr, nullptr, nullptr, nullptr,
        th, nullptr, nullptr);

    // out = relu(BN(th @ Wo + bo)) + x
    conv_wT<<<1024, blk, 0, stream>>>(Wo, Wot);
    gemm16<false, 2><<<g16, blk, 0, stream>>>(th, nullptr, Wot, nullptr,
        bo, nullptr, bn_scale, bn_bias, bn_mean, bn_var, x,
        nullptr, nullptr, out);
}

// Round 9
// 589.115 us; speedup vs baseline: 1.1402x; 1.1402x over previous
//
#include <hip/hip_runtime.h>
#include <math.h>

// Problem constants (B=16, N=2048, C=512)
#define BB 16
#define NN 2048
#define CC 512
#define MM (BB * NN)   // 32768 flattened rows
#define NSPLIT 4       // range-split factor for attention passes

typedef _Float16 half8 __attribute__((ext_vector_type(8)));
typedef _Float16 half4 __attribute__((ext_vector_type(4)));
typedef float floatx4 __attribute__((ext_vector_type(4)));

// async global->LDS, 16B/lane; LDS dest = wave-uniform base + lane*16
#define GLD16(gp, lp) __builtin_amdgcn_global_load_lds( \
    (const __attribute__((address_space(1))) void*)(gp), \
    (__attribute__((address_space(3))) void*)(lp), 16, 0, 0)

// LDS tile layout: 16-row groups, 32 halves (64B) per row, quad(16B)-XOR-swizzled:
// slot quad q' holds global quad q' ^ ((row>>1)&3)  -> b128 frag reads are 2-way
// conflict (free) instead of 8-way. Same XOR on stage & read (self-inverse).
__device__ __forceinline__ int foff(int row16base, int fr, int g4) {
    return (row16base + fr) * 32 + ((g4 ^ ((fr >> 1) & 3)) << 3);
}

// ---------------------------------------------------------------------------
// w2[c] = sum_j Wk[c][j] * bq[j]   (beta helper; bq==0 at runtime)
// ---------------------------------------------------------------------------
__global__ __launch_bounds__(256)
void calc_w2(const float* __restrict__ Wk, const float* __restrict__ bq,
             float* __restrict__ w2)
{
    const int i = blockIdx.x * 256 + threadIdx.x;
    if (i < 512) {
        float s = 0.0f;
        for (int j = 0; j < 512; ++j) s += Wk[i * 512 + j] * bq[j];
        w2[i] = s;
    }
}

// ---------------------------------------------------------------------------
// FUSED: split x (fp32) -> xh + xl (f16 hi/lo), AND bet[m] = x_m . w2.
// Block = 1024 floats = 2 rows; x is already in registers for the split, so
// the dot-partial costs 4 FMA/lane; waves 0,1 -> row 2b, waves 2,3 -> 2b+1.
// Replaces the old calc_beta's separate 64 MB re-read of x.
// ---------------------------------------------------------------------------
__global__ __launch_bounds__(256)
void split_x_beta(const float* __restrict__ x, const float* __restrict__ w2,
                  _Float16* __restrict__ xh, _Float16* __restrict__ xl,
                  float* __restrict__ bet)
{
    __shared__ float part[4];
    const int t = threadIdx.x;
    const size_t i = (size_t)blockIdx.x * 1024 + (size_t)t * 4;
    const float4 v = *(const float4*)(x + i);
    half4 h, l;
    h[0] = (_Float16)v.x; l[0] = (_Float16)(v.x - (float)h[0]);
    h[1] = (_Float16)v.y; l[1] = (_Float16)(v.y - (float)h[1]);
    h[2] = (_Float16)v.z; l[2] = (_Float16)(v.z - (float)h[2]);
    h[3] = (_Float16)v.w; l[3] = (_Float16)(v.w - (float)h[3]);
    *(half4*)(xh + i) = h;
    *(half4*)(xl + i) = l;

    const float4 wv = *(const float4*)(w2 + ((t * 4) & 511));
    float s = v.x * wv.x + v.y * wv.y + v.z * wv.z + v.w * wv.w;
#pragma unroll
    for (int off = 1; off < 64; off <<= 1) s += __shfl_xor(s, off);
    const int w = t >> 6;
    if ((t & 63) == 0) part[w] = s;
    __syncthreads();
    const int m0 = blockIdx.x * 2;
    if (t == 0)   bet[m0]     = part[0] + part[1];
    if (t == 128) bet[m0 + 1] = part[2] + part[3];
}

// ---------------------------------------------------------------------------
// Wt[n*512+k] = f16(W[k*512+n])  (512x512 transpose+convert, tiny)
// ---------------------------------------------------------------------------
__global__ __launch_bounds__(256)
void conv_wT(const float* __restrict__ W, _Float16* __restrict__ Wt)
{
    const int o = blockIdx.x * 256 + threadIdx.x;   // o = n*512 + k
    const int n = o >> 9, k = o & 511;
    Wt[o] = (_Float16)W[k * 512 + n];
}

// ---------------------------------------------------------------------------
// Pt[j][i] = sum_c Wk[j][c]*Wq[i][c]  (= P^T, P = Wq Wk^T), fp32, split-store.
// ---------------------------------------------------------------------------
__global__ __launch_bounds__(256)
void gemm_nt_split(const float* __restrict__ A, const float* __restrict__ Bm,
                   _Float16* __restrict__ outh, _Float16* __restrict__ outl)
{
    __shared__ float As[16][64];
    __shared__ float Bs[16][64];
    const int t = threadIdx.x, tc = t & 15, tr = t >> 4;
    const int j0 = blockIdx.x * 64, i0 = blockIdx.y * 64;
    const int lm = t >> 2, lk4 = (t & 3) << 2;
    float acc[4][4] = {};
    for (int kt = 0; kt < 512; kt += 16) {
        const float4 xa = *(const float4*)(A + (size_t)(j0 + lm) * 512 + kt + lk4);
        As[lk4 + 0][lm] = xa.x; As[lk4 + 1][lm] = xa.y;
        As[lk4 + 2][lm] = xa.z; As[lk4 + 3][lm] = xa.w;
        const float4 xb = *(const float4*)(Bm + (size_t)(i0 + lm) * 512 + kt + lk4);
        Bs[lk4 + 0][lm] = xb.x; Bs[lk4 + 1][lm] = xb.y;
        Bs[lk4 + 2][lm] = xb.z; Bs[lk4 + 3][lm] = xb.w;
        __syncthreads();
#pragma unroll
        for (int k = 0; k < 16; ++k) {
            float av[4], bv[4];
            *(float4*)av = *(const float4*)&As[k][tr * 4];
            *(float4*)bv = *(const float4*)&Bs[k][tc * 4];
#pragma unroll
            for (int i = 0; i < 4; ++i)
#pragma unroll
                for (int j = 0; j < 4; ++j)
                    acc[i][j] = fmaf(av[i], bv[j], acc[i][j]);
        }
        __syncthreads();
    }
#pragma unroll
    for (int i = 0; i < 4; ++i) {
        const int row = j0 + tr * 4 + i;
#pragma unroll
        for (int j = 0; j < 4; ++j) {
            const int col = i0 + tc * 4 + j;
            const float y = acc[i][j];
            const _Float16 h = (_Float16)y;
            outh[row * 512 + col] = h;
            outl[row * 512 + col] = (_Float16)(y - (float)h);
        }
    }
}

// ---------------------------------------------------------------------------
// a-GEMM (3-term split): Y = A @ Bt^T, 128x128 tile, 4 waves, 1-phase
// 4-stream GLD16 staging. EXACT Round-7 proven structure (the R8 per-lane
// lo-operand gather variant regressed: 12 gathers/tile exposed HBM latency
// inside the tile body -> reverted).
// ---------------------------------------------------------------------------
__global__ __launch_bounds__(256)
void gemm16_split(const _Float16* __restrict__ Ah, const _Float16* __restrict__ Al,
                  const _Float16* __restrict__ Bh, const _Float16* __restrict__ Bl,
                  _Float16* __restrict__ oh, _Float16* __restrict__ ol)
{
    __shared__ __align__(16) _Float16 sAh[128 * 32], sBh[128 * 32];
    __shared__ __align__(16) _Float16 sAl[128 * 32], sBl[128 * 32];

    const int t = threadIdx.x, lane = t & 63, w = t >> 6;
    const int m0 = blockIdx.x * 128, n0 = blockIdx.y * 128;
    const int lr4 = lane >> 2;
    const int sw8 = (((lane & 3) ^ ((lr4 >> 1) & 3)) << 3);
    const int fr = lane & 15, g4 = lane >> 4;
    const int wr = (w >> 1) * 64, wc = (w & 1) * 64;

    floatx4 acc[4][4];
#pragma unroll
    for (int i = 0; i < 4; ++i)
#pragma unroll
        for (int j = 0; j < 4; ++j) acc[i][j] = (floatx4){0.f, 0.f, 0.f, 0.f};

    for (int kt = 0; kt < CC; kt += 32) {
#pragma unroll
        for (int c = 0; c < 2; ++c) {
            const int r = w * 32 + c * 16;
            const size_t goA = (size_t)(m0 + r + lr4) * CC + kt + sw8;
            const size_t goB = (size_t)(n0 + r + lr4) * CC + kt + sw8;
            GLD16(Ah + goA, sAh + r * 32);
            GLD16(Bh + goB, sBh + r * 32);
            GLD16(Al + goA, sAl + r * 32);
            GLD16(Bl + goB, sBl + r * 32);
        }
        __syncthreads();

        half8 fa[4], fb[4], fal[4], fbl[4];
#pragma unroll
        for (int rt = 0; rt < 4; ++rt) {
            fa[rt]  = *(const half8*)&sAh[foff(wr + rt * 16, fr, g4)];
            fal[rt] = *(const half8*)&sAl[foff(wr + rt * 16, fr, g4)];
        }
#pragma unroll
        for (int ct = 0; ct < 4; ++ct) {
            fb[ct]  = *(const half8*)&sBh[foff(wc + ct * 16, fr, g4)];
            fbl[ct] = *(const half8*)&sBl[foff(wc + ct * 16, fr, g4)];
        }
#pragma unroll
        for (int rt = 0; rt < 4; ++rt)
#pragma unroll
            for (int ct = 0; ct < 4; ++ct) {
                acc[rt][ct] = __builtin_amdgcn_mfma_f32_16x16x32_f16(
                    fa[rt], fb[ct], acc[rt][ct], 0, 0, 0);
                acc[rt][ct] = __builtin_amdgcn_mfma_f32_16x16x32_f16(
                    fa[rt], fbl[ct], acc[rt][ct], 0, 0, 0);
                acc[rt][ct] = __builtin_amdgcn_mfma_f32_16x16x32_f16(
                    fal[rt], fb[ct], acc[rt][ct], 0, 0, 0);
            }
        __syncthreads();
    }

#pragma unroll
    for (int rt = 0; rt < 4; ++rt)
#pragma unroll
        for (int ct = 0; ct < 4; ++ct) {
            const int col = n0 + wc + ct * 16 + fr;
#pragma unroll
            for (int reg = 0; reg < 4; ++reg) {
                const int row = m0 + wr + rt * 16 + g4 * 4 + reg;
                const float y = acc[rt][ct][reg];
                const _Float16 h = (_Float16)y;
                oh[(size_t)row * CC + col] = h;
                ol[(size_t)row * CC + col] = (_Float16)(y - (float)h);
            }
        }
}

// ---------------------------------------------------------------------------
// Non-split f16 MFMA GEMM: Y[M x 512] = A[M x 512] @ Bt^T. 128x256 tile,
// 4 waves, acc 4x8, 3-buffer depth-2 counted-vmcnt pipeline (proven shape:
// identical to attn_colsum's loop minus the exp epilogue).
// MODE 1: oh = f16((acc + bias[col]) * colsc[row])            (v-GEMM)
// MODE 2: outf = relu(BN(acc + bias)) + xres                  (out-GEMM)
// ---------------------------------------------------------------------------
template<int MODE>
__global__ __launch_bounds__(256, 2)
void gemm16n(const _Float16* __restrict__ Ah, const _Float16* __restrict__ Bh,
             const float* __restrict__ bias, const float* __restrict__ colsc,
             const float* __restrict__ bn_scale, const float* __restrict__ bn_bias,
             const float* __restrict__ bn_mean, const float* __restrict__ bn_var,
             const float* __restrict__ xres,
             _Float16* __restrict__ oh, float* __restrict__ outf)
{
    __shared__ __align__(16) _Float16 sA0[128 * 32], sA1[128 * 32], sA2[128 * 32];
    __shared__ __align__(16) _Float16 sB0[256 * 32], sB1[256 * 32], sB2[256 * 32];

    const int t = threadIdx.x, lane = t & 63, w = t >> 6;
    const int m0 = blockIdx.x * 128, n0 = blockIdx.y * 256;
    const int lr4 = lane >> 2;
    const int sw8 = (((lane & 3) ^ ((lr4 >> 1) & 3)) << 3);
    const int fr = lane & 15, g4 = lane >> 4;
    const int wr = (w >> 1) * 64, wc = (w & 1) * 128;

    floatx4 acc[4][8];
#pragma unroll
    for (int i = 0; i < 4; ++i)
#pragma unroll
        for (int j = 0; j < 8; ++j) acc[i][j] = (floatx4){0.f, 0.f, 0.f, 0.f};

    auto stage = [&](_Float16* Sa, _Float16* Sb, int gt) {
        const int kt = gt * 32;
#pragma unroll
        for (int c = 0; c < 2; ++c) {          // A: 128 rows
            const int r = w * 32 + c * 16;
            GLD16(Ah + (size_t)(m0 + r + lr4) * CC + kt + sw8, Sa + r * 32);
        }
#pragma unroll
        for (int c = 0; c < 4; ++c) {          // B: 256 rows
            const int r = w * 64 + c * 16;
            GLD16(Bh + (size_t)(n0 + r + lr4) * CC + kt + sw8, Sb + r * 32);
        }
    };

    // mode: 0 = stage(t+2)+vmcnt(6), 1 = no stage+vmcnt(0), 2 = tail
    auto tile = [&](const _Float16* Ra, const _Float16* Rb,
                    _Float16* Sa, _Float16* Sb, int gt, int mode) {
        if (mode == 0) stage(Sa, Sb, gt + 2);
        half8 fa[4];
#pragma unroll
        for (int rt = 0; rt < 4; ++rt)
            fa[rt] = *(const half8*)&Ra[foff(wr + rt * 16, fr, g4)];
#pragma unroll
        for (int hh = 0; hh < 2; ++hh) {        // two ct-halves bound VGPRs
            half8 fb[4];
#pragma unroll
            for (int c4 = 0; c4 < 4; ++c4)
                fb[c4] = *(const half8*)&Rb[foff(wc + (hh * 4 + c4) * 16, fr, g4)];
            __builtin_amdgcn_s_setprio(1);
#pragma unroll
            for (int rt = 0; rt < 4; ++rt)
#pragma unroll
                for (int c4 = 0; c4 < 4; ++c4)
                    acc[rt][hh * 4 + c4] = __builtin_amdgcn_mfma_f32_16x16x32_f16(
                        fa[rt], fb[c4], acc[rt][hh * 4 + c4], 0, 0, 0);
            __builtin_amdgcn_s_setprio(0);
        }
        if (mode == 0)      asm volatile("s_waitcnt vmcnt(6)" ::: "memory");
        else if (mode == 1) asm volatile("s_waitcnt vmcnt(0)" ::: "memory");
        __builtin_amdgcn_s_barrier();
        asm volatile("" ::: "memory");
    };

    stage(sA0, sB0, 0);
    stage(sA1, sB1, 1);
    asm volatile("s_waitcnt vmcnt(6)" ::: "memory");
    __builtin_amdgcn_s_barrier();
    asm volatile("" ::: "memory");

#pragma unroll 1
    for (int u = 0; u < 4; ++u) {              // tiles 0..11
        const int gt = u * 3;
        tile(sA0, sB0, sA2, sB2, gt,     0);
        tile(sA1, sB1, sA0, sB0, gt + 1, 0);
        tile(sA2, sB2, sA1, sB1, gt + 2, 0);
    }
    tile(sA0, sB0, sA2, sB2, 12, 0);
    tile(sA1, sB1, sA0, sB0, 13, 0);
    tile(sA2, sB2, nullptr, nullptr, 14, 1);
    tile(sA0, sB0, nullptr, nullptr, 15, 2);

#pragma unroll
    for (int rt = 0; rt < 4; ++rt)
#pragma unroll
        for (int ct = 0; ct < 8; ++ct) {
            const int col = n0 + wc + ct * 16 + fr;
#pragma unroll
            for (int reg = 0; reg < 4; ++reg) {
                const int row = m0 + wr + rt * 16 + g4 * 4 + reg;
                float y = acc[rt][ct][reg];
                if constexpr (MODE == 1) {
                    y = (y + bias[col]) * colsc[row];
                    oh[(size_t)row * CC + col] = (_Float16)y;
                } else {
                    y += bias[col];
                    y = (y - bn_mean[col]) * rsqrtf(bn_var[col] + 1e-5f)
                            * bn_scale[col] + bn_bias[col];
                    y = fmaxf(y, 0.0f) + xres[(size_t)row * CC + col];
                    outf[(size_t)row * CC + col] = y;
                }
            }
        }
}

// ---------------------------------------------------------------------------
// XCD-grouping remaps (proven: FETCH 656 -> 541 MB). Rowstats grid (16,16,4):
// h = bx + 16by + 256bz; xt=(h>>3)&15; g=((h>>7)<<3)|(h&7); b=g&15; sp=g>>4.
// Colsum grid (8,16,4):  h = bx +  8by + 128bz; xt=(h>>3)&7;
//                        g=((h>>6)<<3)|(h&7); b=g&15; sp=g>>4.
// All xt-siblings of a (b,sp) group sit at h == g (mod 8) -> same XCD L2.
// ---------------------------------------------------------------------------
__device__ __forceinline__ void attn_decode3(int& xt, int& b, int& sp) {
    const int h = blockIdx.x + (blockIdx.y << 4) + (blockIdx.z << 8);
    xt = (h >> 3) & 15;
    const int g = ((h >> 7) << 3) | (h & 7);
    b = g & 15;
    sp = g >> 4;
}
__device__ __forceinline__ void attn_decode_col(int& xt, int& b, int& sp) {
    const int h = blockIdx.x + (blockIdx.y << 3) + (blockIdx.z << 7);
    xt = (h >> 3) & 7;
    const int g = ((h >> 6) << 3) | (h & 7);
    b = g & 15;
    sp = g >> 4;
}

// ---------------------------------------------------------------------------
// Pass A: partial online-softmax stats over an n-range of 512.
// Grid (16,16,4), XCD-remapped. Block: 128 m-rows x 2 n-chunks of 256.
// 32 k-tiles total (2 chunks x 16), 3-buffer depth-2 counted-vmcnt pipeline.
// LDS: Ah (hi A) + X per buffer (24 KB x3); al (lo A) goes global->register
// per wave (rows are wave-private), issued FIRST in each body so the
// compiler's auto-wait before its MFMA use is vmcnt(6) -> keeps the t+2
// stage in flight. acc 4x8 (64 MFMA/tile/wave = 2x duty per barrier).
// ---------------------------------------------------------------------------
__global__ __launch_bounds__(256, 2)
void attn_rowstats(const _Float16* __restrict__ ah_, const _Float16* __restrict__ al_,
                   const _Float16* __restrict__ xh_,
                   const float* __restrict__ bet,
                   float* __restrict__ pm, float* __restrict__ pl)
{
    __shared__ __align__(16) _Float16 A0[128 * 32], A1[128 * 32], A2[128 * 32];
    __shared__ __align__(16) _Float16 X0[256 * 32], X1[256 * 32], X2[256 * 32];
    __shared__ float wm[4][64], wl[4][64];

    int xt, b, sp;
    attn_decode3(xt, b, sp);
    const int m0 = xt * 128;
    const int t = threadIdx.x, lane = t & 63, w = t >> 6;
    const int lr4 = lane >> 2;
    const int sw8 = (((lane & 3) ^ ((lr4 >> 1) & 3)) << 3);
    const int fr = lane & 15, g4 = lane >> 4;
    const int wr = (w >> 1) * 64, wc = (w & 1) * 128;
    const size_t bbase = (size_t)b * NN;

    // bet for both 256-wide chunks, preloaded (no mid-loop VMEM)
    float betA[8], betB[8];
#pragma unroll
    for (int ct = 0; ct < 8; ++ct) {
        betA[ct] = bet[bbase + sp * 512 +   0 + wc + ct * 16 + fr];
        betB[ct] = bet[bbase + sp * 512 + 256 + wc + ct * 16 + fr];
    }

    float m_st[4][4], l_st[4][4];
#pragma unroll
    for (int i = 0; i < 4; ++i)
#pragma unroll
        for (int j = 0; j < 4; ++j) { m_st[i][j] = -3.0e38f; l_st[i][j] = 0.0f; }

    floatx4 acc[4][8];
#pragma unroll
    for (int i = 0; i < 4; ++i)
#pragma unroll
        for (int j = 0; j < 8; ++j) acc[i][j] = (floatx4){0.f, 0.f, 0.f, 0.f};

    auto stage = [&](_Float16* Sa, _Float16* Sx, int gt) {
        const int nn0 = sp * 512 + (gt >> 4) * 256;
        const int nkt = (gt & 15) * 32;
#pragma unroll
        for (int c = 0; c < 2; ++c) {          // A-hi: 128 rows
            const int r = w * 32 + c * 16;
            GLD16(ah_ + (bbase + m0 + r + lr4) * CC + nkt + sw8, Sa + r * 32);
        }
#pragma unroll
        for (int c = 0; c < 4; ++c) {          // X: 256 rows
            const int r = w * 64 + c * 16;
            GLD16(xh_ + (bbase + nn0 + r + lr4) * CC + nkt + sw8, Sx + r * 32);
        }
    };

    // mode: 0 = stage(t+2)+vmcnt(6), 1 = no stage+vmcnt(0), 2 = tail
    auto tile = [&](const _Float16* Ra, const _Float16* Rx,
                    _Float16* Sa, _Float16* Sx, int gt, int mode) {
        const int kt = (gt & 15) * 32;
        half8 fal[4];                           // A-lo straight to regs (FIRST)
#pragma unroll
        for (int rt = 0; rt < 4; ++rt)
            fal[rt] = *(const half8*)(al_ + (bbase + m0 + wr + rt * 16 + fr) * CC
                                      + kt + g4 * 8);
        if (mode == 0) stage(Sa, Sx, gt + 2);
        half8 fa[4];
#pragma unroll
        for (int rt = 0; rt < 4; ++rt)
            fa[rt] = *(const half8*)&Ra[foff(wr + rt * 16, fr, g4)];
#pragma unroll
        for (int hh = 0; hh < 2; ++hh) {        // two ct-halves bound VGPRs
            half8 fb[4];
#pragma unroll
            for (int c4 = 0; c4 < 4; ++c4)
                fb[c4] = *(const half8*)&Rx[foff(wc + (hh * 4 + c4) * 16, fr, g4)];
            __builtin_amdgcn_s_setprio(1);
#pragma unroll
            for (int rt = 0; rt < 4; ++rt)
#pragma unroll
                for (int c4 = 0; c4 < 4; ++c4) {
                    acc[rt][hh * 4 + c4] = __builtin_amdgcn_mfma_f32_16x16x32_f16(
                        fa[rt], fb[c4], acc[rt][hh * 4 + c4], 0, 0, 0);
                    acc[rt][hh * 4 + c4] = __builtin_amdgcn_mfma_f32_16x16x32_f16(
                        fal[rt], fb[c4], acc[rt][hh * 4 + c4], 0, 0, 0);
                }
            __builtin_amdgcn_s_setprio(0);
        }
        if ((gt & 15) == 15) {                  // chunk end: softmax update
            const bool c1 = (gt >> 4) != 0;
#pragma unroll
            for (int rt = 0; rt < 4; ++rt)
#pragma unroll
                for (int reg = 0; reg < 4; ++reg) {
                    float v[8];
#pragma unroll
                    for (int ct = 0; ct < 8; ++ct)
                        v[ct] = acc[rt][ct][reg] + (c1 ? betB[ct] : betA[ct]);
                    float mx = v[0];
#pragma unroll
                    for (int ct = 1; ct < 8; ++ct) mx = fmaxf(mx, v[ct]);
                    const float mo = m_st[rt][reg];
                    const float mn = fmaxf(mo, mx);
                    float s = 0.0f;
#pragma unroll
                    for (int ct = 0; ct < 8; ++ct) s += __expf(v[ct] - mn);
                    l_st[rt][reg] = l_st[rt][reg] * __expf(mo - mn) + s;
                    m_st[rt][reg] = mn;
                }
#pragma unroll
            for (int i = 0; i < 4; ++i)
#pragma unroll
                for (int j = 0; j < 8; ++j) acc[i][j] = (floatx4){0.f, 0.f, 0.f, 0.f};
        }
        if (mode == 0)      asm volatile("s_waitcnt vmcnt(6)" ::: "memory");
        else if (mode == 1) asm volatile("s_waitcnt vmcnt(0)" ::: "memory");
        __builtin_amdgcn_s_barrier();
        asm volatile("" ::: "memory");
    };

    stage(A0, X0, 0);
    stage(A1, X1, 1);
    asm volatile("s_waitcnt vmcnt(6)" ::: "memory");
    __builtin_amdgcn_s_barrier();
    asm volatile("" ::: "memory");

#pragma unroll 1
    for (int u = 0; u < 10; ++u) {
        const int gt = u * 3;
        tile(A0, X0, A2, X2, gt,     0);
        tile(A1, X1, A0, X0, gt + 1, 0);
        tile(A2, X2, A1, X1, gt + 2, 0);
    }
    tile(A0, X0, nullptr, nullptr, 30, 1);
    tile(A1, X1, nullptr, nullptr, 31, 2);

    // merge across 16 col-lanes, then across the col-wave pair via LDS
#pragma unroll
    for (int rt = 0; rt < 4; ++rt)
#pragma unroll
        for (int reg = 0; reg < 4; ++reg) {
            float m = m_st[rt][reg], l = l_st[rt][reg];
#pragma unroll
            for (int off = 1; off < 16; off <<= 1) {
                const float mo = __shfl_xor(m, off);
                const float lo = __shfl_xor(l, off);
                const float mn = fmaxf(m, mo);
                l = l * __expf(m - mn) + lo * __expf(mo - mn);
                m = mn;
            }
            if (fr == 0) {
                wm[w][rt * 16 + g4 * 4 + reg] = m;
                wl[w][rt * 16 + g4 * 4 + reg] = l;
            }
        }
    __syncthreads();
    if (t < 128) {
        const int r = t & 63;
        const int wa = (t < 64) ? 0 : 2, wb = wa + 1;
        const float ma = wm[wa][r], mb = wm[wb][r];
        const float M = fmaxf(ma, mb);
        const float L = wl[wa][r] * __expf(ma - M) + wl[wb][r] * __expf(mb - M);
        pm[(size_t)sp * MM + bbase + m0 + t] = M;
        pl[(size_t)sp * MM + bbase + m0 + t] = L;
    }
}

// ---------------------------------------------------------------------------
// rho[m] = M + log(sum_s pl[s]*exp(pm[s]-M)),  M = max_s pm[s]
// ---------------------------------------------------------------------------
__global__ __launch_bounds__(256)
void rho_merge(const float* __restrict__ pm, const float* __restrict__ pl,
               float* __restrict__ rho)
{
    const size_t i = (size_t)blockIdx.x * 256 + threadIdx.x;
    float M = pm[i];
#pragma unroll
    for (int s = 1; s < NSPLIT; ++s) M = fmaxf(M, pm[s * (size_t)MM + i]);
    float L = 0.0f;
#pragma unroll
    for (int s = 0; s < NSPLIT; ++s)
        L += pl[s * (size_t)MM + i] * __expf(pm[s * (size_t)MM + i] - M);
    rho[i] = M + __logf(L);
}

// ---------------------------------------------------------------------------
// Pass B: partial column sums over an m-range of 512.
// Grid (8,16,4), XCD-remapped. Block: 256 n-cols x 4 m-chunks of 128.
// 64 k-tiles, same 3-buffer depth-2 pipeline, al->regs, acc 4x8.
// pc[split][b*NN+n] = sum_{m in range} exp(s + bet[n] - rho[m]).
// ---------------------------------------------------------------------------
__global__ __launch_bounds__(256, 2)
void attn_colsum(const _Float16* __restrict__ ah_, const _Float16* __restrict__ al_,
                 const _Float16* __restrict__ xh_,
                 const float* __restrict__ bet, const float* __restrict__ rho,
                 float* __restrict__ pc)
{
    __shared__ __align__(16) _Float16 A0[128 * 32], A1[128 * 32], A2[128 * 32];
    __shared__ __align__(16) _Float16 X0[256 * 32], X1[256 * 32], X2[256 * 32];
    __shared__ float cred[4][128];

    int xt, b, sp;
    attn_decode_col(xt, b, sp);
    const int n0 = xt * 256;
    const int t = threadIdx.x, lane = t & 63, w = t >> 6;
    const int lr4 = lane >> 2;
    const int sw8 = (((lane & 3) ^ ((lr4 >> 1) & 3)) << 3);
    const int fr = lane & 15, g4 = lane >> 4;
    const int wr = (w >> 1) * 64, wc = (w & 1) * 128;
    const size_t bbase = (size_t)b * NN;

    float bet_r[8];
#pragma unroll
    for (int ct = 0; ct < 8; ++ct)
        bet_r[ct] = bet[bbase + n0 + wc + ct * 16 + fr];

    float csum[8] = {0.f, 0.f, 0.f, 0.f, 0.f, 0.f, 0.f, 0.f};
    floatx4 rr[4];
    floatx4 acc[4][8];
#pragma unroll
    for (int i = 0; i < 4; ++i)
#pragma unroll
        for (int j = 0; j < 8; ++j) acc[i][j] = (floatx4){0.f, 0.f, 0.f, 0.f};

    auto stage = [&](_Float16* Sa, _Float16* Sx, int gt) {
        const int nm0 = sp * 512 + (gt >> 4) * 128;
        const int nkt = (gt & 15) * 32;
#pragma unroll
        for (int c = 0; c < 2; ++c) {          // A-hi: 128 m-rows (chunk)
            const int r = w * 32 + c * 16;
            GLD16(ah_ + (bbase + nm0 + r + lr4) * CC + nkt + sw8, Sa + r * 32);
        }
#pragma unroll
        for (int c = 0; c < 4; ++c) {          // X: 256 n-rows (fixed panel)
            const int r = w * 64 + c * 16;
            GLD16(xh_ + (bbase + n0 + r + lr4) * CC + nkt + sw8, Sx + r * 32);
        }
    };

    auto tile = [&](const _Float16* Ra, const _Float16* Rx,
                    _Float16* Sa, _Float16* Sx, int gt, int mode) {
        const int kt = (gt & 15) * 32;
        const int m0c = sp * 512 + (gt >> 4) * 128;
        if ((gt & 15) == 0) {                   // chunk start: rho -> regs
#pragma unroll
            for (int rt = 0; rt < 4; ++rt)
                rr[rt] = *(const floatx4*)&rho[bbase + m0c + wr + rt * 16 + g4 * 4];
        }
        half8 fal[4];                           // A-lo to regs (FIRST)
#pragma unroll
        for (int rt = 0; rt < 4; ++rt)
            fal[rt] = *(const half8*)(al_ + (bbase + m0c + wr + rt * 16 + fr) * CC
                                      + kt + g4 * 8);
        if (mode == 0) stage(Sa, Sx, gt + 2);
        half8 fa[4];
#pragma unroll
        for (int rt = 0; rt < 4; ++rt)
            fa[rt] = *(const half8*)&Ra[foff(wr + rt * 16, fr, g4)];
#pragma unroll
        for (int hh = 0; hh < 2; ++hh) {
            half8 fb[4];
#pragma unroll
            for (int c4 = 0; c4 < 4; ++c4)
                fb[c4] = *(const half8*)&Rx[foff(wc + (hh * 4 + c4) * 16, fr, g4)];
            __builtin_amdgcn_s_setprio(1);
#pragma unroll
            for (int rt = 0; rt < 4; ++rt)
#pragma unroll
                for (int c4 = 0; c4 < 4; ++c4) {
                    acc[rt][hh * 4 + c4] = __builtin_amdgcn_mfma_f32_16x16x32_f16(
                        fa[rt], fb[c4], acc[rt][hh * 4 + c4], 0, 0, 0);
                    acc[rt][hh * 4 + c4] = __builtin_amdgcn_mfma_f32_16x16x32_f16(
                        fal[rt], fb[c4], acc[rt][hh * 4 + c4], 0, 0, 0);
                }
            __builtin_amdgcn_s_setprio(0);
        }
        if ((gt & 15) == 15) {                  // chunk end: colsum accumulate
#pragma unroll
            for (int rt = 0; rt < 4; ++rt)
#pragma unroll
                for (int reg = 0; reg < 4; ++reg) {
                    const float r = rr[rt][reg];
#pragma unroll
                    for (int ct = 0; ct < 8; ++ct)
                        csum[ct] += __expf(acc[rt][ct][reg] + bet_r[ct] - r);
                }
#pragma unroll
            for (int i = 0; i < 4; ++i)
#pragma unroll
                for (int j = 0; j < 8; ++j) acc[i][j] = (floatx4){0.f, 0.f, 0.f, 0.f};
        }
        if (mode == 0)      asm volatile("s_waitcnt vmcnt(6)" ::: "memory");
        else if (mode == 1) asm volatile("s_waitcnt vmcnt(0)" ::: "memory");
        __builtin_amdgcn_s_barrier();
        asm volatile("" ::: "memory");
    };

    stage(A0, X0, 0);
    stage(A1, X1, 1);
    asm volatile("s_waitcnt vmcnt(6)" ::: "memory");
    __builtin_amdgcn_s_barrier();
    asm volatile("" ::: "memory");

#pragma unroll 1
    for (int u = 0; u < 20; ++u) {
        const int gt = u * 3;
        tile(A0, X0, A2, X2, gt,     0);
        tile(A1, X1, A0, X0, gt + 1, 0);
        tile(A2, X2, A1, X1, gt + 2, 0);
    }
    tile(A0, X0, A2, X2, 60, 0);
    tile(A1, X1, A0, X0, 61, 0);
    tile(A2, X2, nullptr, nullptr, 62, 1);
    tile(A0, X0, nullptr, nullptr, 63, 2);

    // reduce over the 4 row-lane groups, then across the row-wave pair
#pragma unroll
    for (int ct = 0; ct < 8; ++ct) {
        csum[ct] += __shfl_xor(csum[ct], 16);
        csum[ct] += __shfl_xor(csum[ct], 32);
    }
    if (lane < 16)
#pragma unroll
        for (int ct = 0; ct < 8; ++ct) cred[w][ct * 16 + lane] = csum[ct];
    __syncthreads();
    if (t < 256) {
        const int c = t & 127;
        const float s = (t < 128) ? (cred[0][c] + cred[2][c])
                                  : (cred[1][c] + cred[3][c]);
        pc[(size_t)sp * MM + bbase + n0 + t] = s;
    }
}

// ---------------------------------------------------------------------------
// colsc[n] = c/(eps+c), c = sum over splits of pc
// ---------------------------------------------------------------------------
__global__ __launch_bounds__(256)
void colsc_merge(const float* __restrict__ pc, float* __restrict__ colsc)
{
    const size_t i = (size_t)blockIdx.x * 256 + threadIdx.x;
    float c = 0.0f;
#pragma unroll
    for (int s = 0; s < NSPLIT; ++s) c += pc[s * (size_t)MM + i];
    colsc[i] = c / (1e-9f + c);
}

// ---------------------------------------------------------------------------
// Workspace (128 MiB): xh|xl|ah|al (4 x M*C f16). th aliases al; Wvt/Wot
// go into ah (dead after passB). Small scratch in d_out (dead before the
// final out-GEMM writes it).
// ---------------------------------------------------------------------------
extern "C" void kernel_launch(void* const* d_in, const int* in_sizes, int n_in,
                              void* d_out, int out_size, void* d_ws, size_t ws_size,
                              hipStream_t stream)
{
    const float* x        = (const float*)d_in[0];
    const float* Wq       = (const float*)d_in[1];
    const float* bq       = (const float*)d_in[2];
    const float* Wk       = (const float*)d_in[3];
    const float* bk       = (const float*)d_in[4];   (void)bk;  // softmax-invariant
    const float* Wv       = (const float*)d_in[5];
    const float* bv       = (const float*)d_in[6];
    const float* Wo       = (const float*)d_in[7];
    const float* bo       = (const float*)d_in[8];
    const float* bn_scale = (const float*)d_in[9];
    const float* bn_bias  = (const float*)d_in[10];
    const float* bn_mean  = (const float*)d_in[11];
    const float* bn_var   = (const float*)d_in[12];
    float* out = (float*)d_out;

    const size_t MMC = (size_t)MM * CC;   // 16,777,216
    _Float16* xh = (_Float16*)d_ws;
    _Float16* xl = xh + MMC;
    _Float16* ah = xl + MMC;
    _Float16* al = ah + MMC;
    _Float16* th  = al;                    // v-GEMM output aliases al
    _Float16* Wvt = ah;                    // converted after passB (ah dead)
    _Float16* Wot = ah + 512 * 512;

    // small scratch in d_out (all consumed before the final GEMM writes out)
    char* ob = (char*)d_out;
    _Float16* Pth = (_Float16*)(ob);                        //  512 KiB
    _Float16* Ptl = (_Float16*)(ob + (1u << 19));           //  512 KiB
    float* w2     = (float*)(ob + (2u << 19));              //    2 KiB
    float* bet    = (float*)(ob + (2u << 19) + 8192);       //  128 KiB
    float* rho    = (float*)(ob + 1318912);                 //  128 KiB
    float* colsc  = (float*)(ob + 1449984);                 //  128 KiB
    float* pm     = (float*)(ob + 1581056);                 //  512 KiB
    float* pl     = (float*)(ob + 2105344);                 //  512 KiB
    float* pc     = (float*)(ob + 2629632);                 //  512 KiB

    const dim3 blk(256);
    const dim3 ga(MM / 128, CC / 128);         // 256 x 4 (a-GEMM, 128x128)
    const dim3 gn(MM / 128, CC / 256);         // 256 x 2 (v/out-GEMM, 128x256)
    const dim3 grow(NN / 128, BB, NSPLIT);     // 16 x 16 x 4 (XCD-remapped)
    const dim3 gcol(NN / 256, BB, NSPLIT);     //  8 x 16 x 4 (XCD-remapped)

    calc_w2<<<2, blk, 0, stream>>>(Wk, bq, w2);
    split_x_beta<<<MMC / 1024, blk, 0, stream>>>(x, w2, xh, xl, bet);
    gemm_nt_split<<<dim3(8, 8), blk, 0, stream>>>(Wk, Wq, Pth, Ptl);

    // a = x @ (Wq Wk^T), split-stored (3-term)
    gemm16_split<<<ga, blk, 0, stream>>>(xh, xl, Pth, Ptl, ah, al);

    attn_rowstats<<<grow, blk, 0, stream>>>(ah, al, xh, bet, pm, pl);
    rho_merge<<<MM / 256, blk, 0, stream>>>(pm, pl, rho);
    attn_colsum<<<gcol, blk, 0, stream>>>(ah, al, xh, bet, rho, pc);
    colsc_merge<<<MM / 256, blk, 0, stream>>>(pc, colsc);

    // th = f16(colsc[row] * (x @ Wv + bv))
    conv_wT<<<1024, blk, 0, stream>>>(Wv, Wvt);
    gemm16n<1><<<gn, blk, 0, stream>>>(xh, Wvt, bv, colsc,
        nullptr, nullptr, nullptr, nullptr, nullptr, th, nullptr);

    // out = relu(BN(th @ Wo + bo)) + x
    conv_wT<<<1024, blk, 0, stream>>>(Wo, Wot);
    gemm16n<2><<<gn, blk, 0, stream>>>(th, Wot, bo, nullptr,
        bn_scale, bn_bias, bn_mean, bn_var, x, nullptr, out);
}